// Round 5
// baseline (146.370 us; speedup 1.0000x reference)
//
#include <hip/hip_runtime.h>

// YOLO-style loss: pred/target (N, 7, 7, 30) f32 -> 5 scalar losses.
// Direct global->VGPR streaming (no LDS anywhere in the data path).
// One lane owns TWO cells (240 B = 15 x 16B-aligned float4 per tensor),
// loaded as 30 global_load_dwordx4 per iteration; all accesses dense and
// 16B-aligned. Responsible-box select via ternaries (compile-time indices
// only -> no scratch). No atomics: per-block partials -> d_ws, second
// kernel reduces.

#define S_GRID 7
#define D_CH   30
#define THREADS 256
#define GRID_BLOCKS 1568   // 1568*256 threads * 2 pairs = 802,816 pairs exactly

// Per-cell loss; P/T must be indexable with compile-time-constant offsets
// (they may point into VGPR-resident arrays). NO runtime indexing inside.
__device__ __forceinline__ void cell_loss(const float* __restrict__ P,
                                          const float* __restrict__ T,
    float& lxy, float& lwh, float& lobj, float& lnoobj, float& lcls)
{
    const float cellw = 1.0f / (float)S_GRID;

    const float t4 = T[4];
    const float obj   = (t4 == 1.0f) ? 1.0f : 0.0f;
    const float noobj = (t4 == 0.0f) ? 1.0f : 0.0f;

    // target box 0 in ltrb
    const float tlx = T[0] * cellw - T[2] * 0.5f;
    const float tly = T[1] * cellw - T[3] * 0.5f;
    const float trx = T[0] * cellw + T[2] * 0.5f;
    const float tby = T[1] * cellw + T[3] * 0.5f;
    const float area_t = (trx - tlx) * (tby - tly);

    float iou[2];
    #pragma unroll
    for (int b = 0; b < 2; ++b) {   // b compile-time after unroll
        const float px = P[b * 5 + 0], py = P[b * 5 + 1];
        const float pw = P[b * 5 + 2], ph = P[b * 5 + 3];
        const float plx = px * cellw - pw * 0.5f;
        const float ply = py * cellw - ph * 0.5f;
        const float prx = px * cellw + pw * 0.5f;
        const float pby = py * cellw + ph * 0.5f;
        const float ltx = fmaxf(plx, tlx);
        const float lty = fmaxf(ply, tly);
        const float rbx = fminf(prx, trx);
        const float rby = fminf(pby, tby);
        const float wx = fmaxf(rbx - ltx, 0.0f);
        const float wy = fmaxf(rby - lty, 0.0f);
        const float inter = wx * wy;
        const float area_p = (prx - plx) * (pby - ply);
        iou[b] = inter / (area_p + area_t - inter);
    }

    // argmax first-occurrence tie-break: box 1 only if strictly greater
    const bool sel = iou[1] > iou[0];
    const float riou = fmaxf(iou[0], iou[1]);

    // responsible box via cndmask selects (no runtime indexing)
    const float pbx = sel ? P[5] : P[0];
    const float pby2 = sel ? P[6] : P[1];
    const float pbw = sel ? P[7] : P[2];
    const float pbh = sel ? P[8] : P[3];
    const float pbc = sel ? P[9] : P[4];
    const float tbx = sel ? T[5] : T[0];
    const float tby2 = sel ? T[6] : T[1];
    const float tbw = sel ? T[7] : T[2];
    const float tbh = sel ? T[8] : T[3];

    const float dx = tbx - pbx;
    const float dy = tby2 - pby2;
    lxy += obj * (dx * dx + dy * dy);

    const float dw = sqrtf(tbw) - sqrtf(pbw);
    const float dh = sqrtf(tbh) - sqrtf(pbh);
    lwh += obj * (dw * dw + dh * dh);

    const float dc = riou - pbc;
    lobj += obj * (dc * dc);

    const float d4 = T[4] - P[4];
    const float d9 = T[9] - P[9];
    lnoobj += noobj * (d4 * d4 + d9 * d9);

    float cs = 0.f;
    #pragma unroll
    for (int c = 10; c < 30; ++c) {
        const float d = T[c] - P[c];
        cs += d * d;
    }
    lcls += obj * cs;
}

__global__ __launch_bounds__(THREADS) void yolo_loss_partial(
    const float* __restrict__ pred, const float* __restrict__ tgt,
    float* __restrict__ ws, long long totalPairs, long long totalCells)
{
    const int tid = threadIdx.x;
    float lxy = 0.f, lwh = 0.f, lobj = 0.f, lnoobj = 0.f, lcls = 0.f;

    const long long stride = (long long)gridDim.x * THREADS;
    for (long long pair = (long long)blockIdx.x * THREADS + tid;
         pair < totalPairs; pair += stride) {
        const float4* gp = reinterpret_cast<const float4*>(pred + pair * 60);
        const float4* gt = reinterpret_cast<const float4*>(tgt  + pair * 60);

        // 30 independent dwordx4 loads; SROA'd to scalars (const indices)
        float p[60], t[60];
        #pragma unroll
        for (int j = 0; j < 15; ++j) {
            const float4 v = gp[j];
            p[4 * j] = v.x; p[4 * j + 1] = v.y; p[4 * j + 2] = v.z; p[4 * j + 3] = v.w;
        }
        #pragma unroll
        for (int j = 0; j < 15; ++j) {
            const float4 v = gt[j];
            t[4 * j] = v.x; t[4 * j + 1] = v.y; t[4 * j + 2] = v.z; t[4 * j + 3] = v.w;
        }

        cell_loss(p,      t,      lxy, lwh, lobj, lnoobj, lcls);
        cell_loss(p + 30, t + 30, lxy, lwh, lobj, lnoobj, lcls);
    }

    // odd trailing cell (dead for this shape): direct from global
    if (blockIdx.x == 0 && tid == 0 && (totalCells & 1LL)) {
        const long long c = totalCells - 1;
        cell_loss(pred + c * D_CH, tgt + c * D_CH, lxy, lwh, lobj, lnoobj, lcls);
    }

    // block reduction: wave shuffle -> LDS across waves -> ws store
    __shared__ float red[THREADS / 64][5];
    #pragma unroll
    for (int off = 32; off > 0; off >>= 1) {
        lxy    += __shfl_down(lxy, off);
        lwh    += __shfl_down(lwh, off);
        lobj   += __shfl_down(lobj, off);
        lnoobj += __shfl_down(lnoobj, off);
        lcls   += __shfl_down(lcls, off);
    }
    const int wave = tid >> 6;
    const int lane = tid & 63;
    if (lane == 0) {
        red[wave][0] = lxy;
        red[wave][1] = lwh;
        red[wave][2] = lobj;
        red[wave][3] = lnoobj;
        red[wave][4] = lcls;
    }
    __syncthreads();
    if (tid < 5) {
        float v = 0.f;
        #pragma unroll
        for (int w = 0; w < THREADS / 64; ++w) v += red[w][tid];
        ws[(long long)blockIdx.x * 5 + tid] = v;
    }
}

__global__ __launch_bounds__(256) void yolo_loss_reduce(
    const float* __restrict__ ws, float* __restrict__ out,
    int nParts, float inv_n)
{
    __shared__ float red[4][5];
    const int tid = threadIdx.x;
    float s0 = 0.f, s1 = 0.f, s2 = 0.f, s3 = 0.f, s4 = 0.f;
    for (int b = tid; b < nParts; b += 256) {
        const float* p = ws + (long long)b * 5;
        s0 += p[0]; s1 += p[1]; s2 += p[2]; s3 += p[3]; s4 += p[4];
    }
    #pragma unroll
    for (int off = 32; off > 0; off >>= 1) {
        s0 += __shfl_down(s0, off);
        s1 += __shfl_down(s1, off);
        s2 += __shfl_down(s2, off);
        s3 += __shfl_down(s3, off);
        s4 += __shfl_down(s4, off);
    }
    const int wave = tid >> 6;
    const int lane = tid & 63;
    if (lane == 0) {
        red[wave][0] = s0; red[wave][1] = s1; red[wave][2] = s2;
        red[wave][3] = s3; red[wave][4] = s4;
    }
    __syncthreads();
    if (tid < 5) {
        float v = 0.f;
        #pragma unroll
        for (int w = 0; w < 4; ++w) v += red[w][tid];
        out[tid] = v * inv_n;
    }
}

extern "C" void kernel_launch(void* const* d_in, const int* in_sizes, int n_in,
                              void* d_out, int out_size, void* d_ws, size_t ws_size,
                              hipStream_t stream) {
    const float* pred = (const float*)d_in[0];
    const float* tgt  = (const float*)d_in[1];
    float* out = (float*)d_out;
    float* ws  = (float*)d_ws;

    const long long totalFloats = (long long)in_sizes[0];
    const long long totalCells = totalFloats / D_CH;            // N*S*S
    const long long n = totalCells / (S_GRID * S_GRID);         // N
    const float inv_n = 1.0f / (float)n;

    const long long totalPairs = totalCells / 2;
    long long needed = (totalPairs + THREADS - 1) / THREADS;
    int blocks = (int)((needed < GRID_BLOCKS) ? needed : GRID_BLOCKS);
    if (blocks < 1) blocks = 1;

    yolo_loss_partial<<<blocks, THREADS, 0, stream>>>(pred, tgt, ws, totalPairs, totalCells);
    yolo_loss_reduce<<<1, 256, 0, stream>>>(ws, out, blocks, inv_n);
}

// Round 6
// 72.949 us; speedup vs baseline: 2.0065x; 2.0065x over previous
//
#include <hip/hip_runtime.h>

// YOLO-style loss: pred/target (N, 7, 7, 30) f32 -> 5 scalar losses.
// HBM-streaming reduction. Persistent blocks grid-stride over 256-cell tiles;
// each tile (pred+tgt, 61440 B) staged to LDS with 15 unrolled float4 loads
// per thread (deep in-flight pipeline); one thread computes one cell.
// NO global atomics: per-block partials -> d_ws, tiny second kernel reduces.
//
// Round-6 note: this is the round-2 schedule, reverted. Rounds 2/3/4
// (three different pipelines, 2/10/5 blocks/CU) all converge to
// 5.3-5.4 TB/s aggregate = 85% of copy BW, matching the best measured
// streaming-reduction kernels on gfx950. Round 5 (no LDS, per-lane
// records) over-fetched 2.4x via L1 thrash and regressed 2x.

#define S_GRID 7
#define D_CH   30
#define CELLS_PER_TILE 256
#define TILE_F4 ((CELLS_PER_TILE * D_CH) / 4)   // 1920 float4 per tensor
#define BOTH_F4 (2 * TILE_F4)                   // 3840 float4 staged
#define THREADS 256
#define GRID_BLOCKS 1024

__global__ __launch_bounds__(THREADS) void yolo_loss_partial(
    const float* __restrict__ pred, const float* __restrict__ tgt,
    float* __restrict__ ws, int nTiles, long long totalCells)
{
    __shared__ float4 stage[BOTH_F4];             // pred tile then tgt tile
    __shared__ float red[THREADS / 64][5];

    const int tid = threadIdx.x;
    const float* sp = reinterpret_cast<const float*>(stage);
    const float* st = reinterpret_cast<const float*>(stage + TILE_F4);

    float lxy = 0.f, lwh = 0.f, lobj = 0.f, lnoobj = 0.f, lcls = 0.f;

    for (int tile = blockIdx.x; tile < nTiles; tile += gridDim.x) {
        const long long cell0 = (long long)tile * CELLS_PER_TILE;
        const float4* gp4 = reinterpret_cast<const float4*>(pred + cell0 * D_CH);
        const float4* gt4 = reinterpret_cast<const float4*>(tgt + cell0 * D_CH);

        __syncthreads();   // previous iteration's readers done before overwrite

        const bool full = (cell0 + CELLS_PER_TILE) <= totalCells;
        if (full) {
            // 15 independent float4 loads per thread, fully unrolled -> deep MLP
            #pragma unroll
            for (int j = 0; j < 15; ++j) {
                const int k = tid + j * THREADS;
                const float4* src = (k < TILE_F4) ? (gp4 + k) : (gt4 + (k - TILE_F4));
                stage[k] = *src;
            }
        } else {
            const long long totalFloats = totalCells * (long long)D_CH;
            const long long baseF = cell0 * (long long)D_CH;
            float* s = reinterpret_cast<float*>(stage);
            for (int f = tid; f < CELLS_PER_TILE * D_CH; f += THREADS) {
                const bool ok = (baseF + f) < totalFloats;
                s[f]                      = ok ? pred[baseF + f] : 0.f;
                s[TILE_F4 * 4 + f]        = ok ? tgt[baseF + f]  : 0.f;
            }
        }
        __syncthreads();

        if (cell0 + tid < totalCells) {
            const float* P = sp + tid * D_CH;
            const float* T = st + tid * D_CH;
            const float cellw = 1.0f / (float)S_GRID;

            const float t4 = T[4];
            const float obj   = (t4 == 1.0f) ? 1.0f : 0.0f;
            const float noobj = (t4 == 0.0f) ? 1.0f : 0.0f;

            // target box 0 in ltrb
            const float tlx = T[0] * cellw - T[2] * 0.5f;
            const float tly = T[1] * cellw - T[3] * 0.5f;
            const float trx = T[0] * cellw + T[2] * 0.5f;
            const float tby = T[1] * cellw + T[3] * 0.5f;
            const float area_t = (trx - tlx) * (tby - tly);

            float iou0 = 0.f, iou1 = 0.f;
            #pragma unroll
            for (int b = 0; b < 2; ++b) {
                const float* Pb = P + b * 5;
                const float plx = Pb[0] * cellw - Pb[2] * 0.5f;
                const float ply = Pb[1] * cellw - Pb[3] * 0.5f;
                const float prx = Pb[0] * cellw + Pb[2] * 0.5f;
                const float pby = Pb[1] * cellw + Pb[3] * 0.5f;
                const float ltx = fmaxf(plx, tlx);
                const float lty = fmaxf(ply, tly);
                const float rbx = fminf(prx, trx);
                const float rby = fminf(pby, tby);
                const float wx = fmaxf(rbx - ltx, 0.0f);
                const float wy = fmaxf(rby - lty, 0.0f);
                const float inter = wx * wy;
                const float area_p = (prx - plx) * (pby - ply);
                const float v = inter / (area_p + area_t - inter);
                if (b == 0) iou0 = v; else iou1 = v;
            }

            // argmax first-occurrence tie-break: idx 1 only if strictly greater
            const int bi = (iou1 > iou0) ? 1 : 0;
            const float riou = fmaxf(iou0, iou1);

            const float* Pb = P + bi * 5;
            const float* Tb = T + bi * 5;
            const float dx = Tb[0] - Pb[0];
            const float dy = Tb[1] - Pb[1];
            lxy += obj * (dx * dx + dy * dy);

            const float dw = sqrtf(Tb[2]) - sqrtf(Pb[2]);
            const float dh = sqrtf(Tb[3]) - sqrtf(Pb[3]);
            lwh += obj * (dw * dw + dh * dh);

            const float dc = riou - Pb[4];
            lobj += obj * (dc * dc);

            const float d4 = T[4] - P[4];
            const float d9 = T[9] - P[9];
            lnoobj += noobj * (d4 * d4 + d9 * d9);

            float cs = 0.f;
            #pragma unroll
            for (int c = 10; c < 30; ++c) {
                const float d = T[c] - P[c];
                cs += d * d;
            }
            lcls += obj * cs;
        }
    }

    // ---- block reduction: wave(64) shuffle -> LDS across waves -> ws store
    #pragma unroll
    for (int off = 32; off > 0; off >>= 1) {
        lxy    += __shfl_down(lxy, off);
        lwh    += __shfl_down(lwh, off);
        lobj   += __shfl_down(lobj, off);
        lnoobj += __shfl_down(lnoobj, off);
        lcls   += __shfl_down(lcls, off);
    }
    const int wave = tid >> 6;
    const int lane = tid & 63;
    if (lane == 0) {
        red[wave][0] = lxy;
        red[wave][1] = lwh;
        red[wave][2] = lobj;
        red[wave][3] = lnoobj;
        red[wave][4] = lcls;
    }
    __syncthreads();
    if (tid < 5) {
        float v = 0.f;
        #pragma unroll
        for (int w = 0; w < THREADS / 64; ++w) v += red[w][tid];
        ws[(long long)blockIdx.x * 5 + tid] = v;
    }
}

__global__ __launch_bounds__(256) void yolo_loss_reduce(
    const float* __restrict__ ws, float* __restrict__ out,
    int nParts, float inv_n)
{
    __shared__ float red[4][5];
    const int tid = threadIdx.x;
    float s0 = 0.f, s1 = 0.f, s2 = 0.f, s3 = 0.f, s4 = 0.f;
    for (int b = tid; b < nParts; b += 256) {
        const float* p = ws + (long long)b * 5;
        s0 += p[0]; s1 += p[1]; s2 += p[2]; s3 += p[3]; s4 += p[4];
    }
    #pragma unroll
    for (int off = 32; off > 0; off >>= 1) {
        s0 += __shfl_down(s0, off);
        s1 += __shfl_down(s1, off);
        s2 += __shfl_down(s2, off);
        s3 += __shfl_down(s3, off);
        s4 += __shfl_down(s4, off);
    }
    const int wave = tid >> 6;
    const int lane = tid & 63;
    if (lane == 0) {
        red[wave][0] = s0; red[wave][1] = s1; red[wave][2] = s2;
        red[wave][3] = s3; red[wave][4] = s4;
    }
    __syncthreads();
    if (tid < 5) {
        float v = 0.f;
        #pragma unroll
        for (int w = 0; w < 4; ++w) v += red[w][tid];
        out[tid] = v * inv_n;
    }
}

extern "C" void kernel_launch(void* const* d_in, const int* in_sizes, int n_in,
                              void* d_out, int out_size, void* d_ws, size_t ws_size,
                              hipStream_t stream) {
    const float* pred = (const float*)d_in[0];
    const float* tgt  = (const float*)d_in[1];
    float* out = (float*)d_out;
    float* ws  = (float*)d_ws;

    const long long totalFloats = (long long)in_sizes[0];
    const long long totalCells = totalFloats / D_CH;                    // N*S*S
    const long long n = totalCells / (S_GRID * S_GRID);                 // N
    const float inv_n = 1.0f / (float)n;

    const int nTiles = (int)((totalCells + CELLS_PER_TILE - 1) / CELLS_PER_TILE);
    const int blocks = (nTiles < GRID_BLOCKS) ? nTiles : GRID_BLOCKS;

    yolo_loss_partial<<<blocks, THREADS, 0, stream>>>(pred, tgt, ws, nTiles, totalCells);
    yolo_loss_reduce<<<1, 256, 0, stream>>>(ws, out, blocks, inv_n);
}